// Round 1
// baseline (160.262 us; speedup 1.0000x reference)
//
#include <hip/hip_runtime.h>

#define NG     1024
#define W_IMG  192
#define H_IMG  192
#define HW     (W_IMG * H_IMG)
#define PSTR   12   // floats per gaussian param record (padded for float4)

// param record layout: [gx, gy, radii, opa_eff, conA, conB, conC, r, g, b, pad, pad]

// ---------------------------------------------------------------------------
// Kernel 1: per-gaussian preprocess
// ---------------------------------------------------------------------------
__global__ __launch_bounds__(64) void preprocess_kernel(
    const float* __restrict__ means3D, const float* __restrict__ scales,
    const float* __restrict__ rotations, const float* __restrict__ opacities,
    const float* __restrict__ shs, const float* __restrict__ viewm,
    const float* __restrict__ projm, const float* __restrict__ campos,
    float* __restrict__ params, float* __restrict__ keys,
    float* __restrict__ outp)
{
    const int i = blockIdx.x * 64 + threadIdx.x;
    if (i >= NG) return;

    const float mx = means3D[i * 3 + 0];
    const float my = means3D[i * 3 + 1];
    const float mz = means3D[i * 3 + 2];

    // ---- SH degree-3 color ----
    float dxc = mx - campos[0], dyc = my - campos[1], dzc = mz - campos[2];
    float nrm = sqrtf(dxc * dxc + dyc * dyc + dzc * dzc);
    float x = dxc / nrm, y = dyc / nrm, z = dzc / nrm;
    float xx = x * x, yy = y * y, zz = z * z;
    float xy = x * y, yz = y * z, xz = x * z;

    float basis[16];
    basis[0]  = 0.28209479177387814f;
    basis[1]  = -0.4886025119029199f * y;
    basis[2]  =  0.4886025119029199f * z;
    basis[3]  = -0.4886025119029199f * x;
    basis[4]  =  1.0925484305920792f * xy;
    basis[5]  = -1.0925484305920792f * yz;
    basis[6]  =  0.31539156525252005f * (2.f * zz - xx - yy);
    basis[7]  = -1.0925484305920792f * xz;
    basis[8]  =  0.5462742152960396f * (xx - yy);
    basis[9]  = -0.5900435899266435f * y * (3.f * xx - yy);
    basis[10] =  2.890611442640554f  * xy * z;
    basis[11] = -0.4570457994644658f * y * (4.f * zz - xx - yy);
    basis[12] =  0.3731763325901154f * z * (2.f * zz - 3.f * xx - 3.f * yy);
    basis[13] = -0.4570457994644658f * x * (4.f * zz - xx - yy);
    basis[14] =  1.445305721320277f  * z * (xx - yy);
    basis[15] = -0.5900435899266435f * x * (xx - yy - 3.f * zz);

    float cr = 0.f, cg = 0.f, cb = 0.f;
#pragma unroll
    for (int k = 0; k < 16; ++k) {
        float b = basis[k];
        cr += b * shs[(i * 16 + k) * 3 + 0];
        cg += b * shs[(i * 16 + k) * 3 + 1];
        cb += b * shs[(i * 16 + k) * 3 + 2];
    }
    cr = fmaxf(cr + 0.5f, 0.f);
    cg = fmaxf(cg + 0.5f, 0.f);
    cb = fmaxf(cb + 0.5f, 0.f);

    // ---- cov3d = (R*S)(R*S)^T ----
    float qr = rotations[i * 4 + 0], qx = rotations[i * 4 + 1];
    float qy = rotations[i * 4 + 2], qz = rotations[i * 4 + 3];
    float sx = scales[i * 3 + 0], sy = scales[i * 3 + 1], sz = scales[i * 3 + 2];
    float R00 = 1.f - 2.f * (qy * qy + qz * qz), R01 = 2.f * (qx * qy - qr * qz), R02 = 2.f * (qx * qz + qr * qy);
    float R10 = 2.f * (qx * qy + qr * qz), R11 = 1.f - 2.f * (qx * qx + qz * qz), R12 = 2.f * (qy * qz - qr * qx);
    float R20 = 2.f * (qx * qz - qr * qy), R21 = 2.f * (qy * qz + qr * qx), R22 = 1.f - 2.f * (qx * qx + qy * qy);
    float M00 = R00 * sx, M01 = R01 * sy, M02 = R02 * sz;
    float M10 = R10 * sx, M11 = R11 * sy, M12 = R12 * sz;
    float M20 = R20 * sx, M21 = R21 * sy, M22 = R22 * sz;
    float S00 = M00 * M00 + M01 * M01 + M02 * M02;
    float S01 = M00 * M10 + M01 * M11 + M02 * M12;
    float S02 = M00 * M20 + M01 * M21 + M02 * M22;
    float S11 = M10 * M10 + M11 * M11 + M12 * M12;
    float S12 = M10 * M20 + M11 * M21 + M12 * M22;
    float S22 = M20 * M20 + M21 * M21 + M22 * M22;

    // ---- view / proj transform ----
    float pv0 = viewm[0] * mx + viewm[1] * my + viewm[2]  * mz + viewm[3];
    float pv1 = viewm[4] * mx + viewm[5] * my + viewm[6]  * mz + viewm[7];
    float pv2 = viewm[8] * mx + viewm[9] * my + viewm[10] * mz + viewm[11];
    float ph0 = projm[0]  * mx + projm[1]  * my + projm[2]  * mz + projm[3];
    float ph1 = projm[4]  * mx + projm[5]  * my + projm[6]  * mz + projm[7];
    float ph3 = projm[12] * mx + projm[13] * my + projm[14] * mz + projm[15];
    float pp0 = ph0 / (ph3 + 1e-7f);
    float pp1 = ph1 / (ph3 + 1e-7f);
    float gx = ((pp0 + 1.f) * (float)W_IMG - 1.f) * 0.5f;
    float gy = ((pp1 + 1.f) * (float)H_IMG - 1.f) * 0.5f;

    float depth = pv2;
    bool in_front = depth > 0.2f;
    float tz = in_front ? depth : 1.f;
    const float lim = 1.3f * 0.5f;   // 1.3 * TANFOV
    float txv = fminf(fmaxf(pv0 / tz, -lim), lim) * tz;
    float tyv = fminf(fmaxf(pv1 / tz, -lim), lim) * tz;
    const float fx = (float)W_IMG / (2.f * 0.5f);
    const float fy = (float)H_IMG / (2.f * 0.5f);
    float J00 = fx / tz, J02 = -fx * txv / (tz * tz);
    float J11 = fy / tz, J12 = -fy * tyv / (tz * tz);

    // T2 = J @ view[:3,:3]   (2x3)
    float T00 = J00 * viewm[0] + J02 * viewm[8];
    float T01 = J00 * viewm[1] + J02 * viewm[9];
    float T02 = J00 * viewm[2] + J02 * viewm[10];
    float T10 = J11 * viewm[4] + J12 * viewm[8];
    float T11 = J11 * viewm[5] + J12 * viewm[9];
    float T12 = J11 * viewm[6] + J12 * viewm[10];

    // cov2d = T2 S T2^T
    float u0 = T00 * S00 + T01 * S01 + T02 * S02;
    float u1 = T00 * S01 + T01 * S11 + T02 * S12;
    float u2 = T00 * S02 + T01 * S12 + T02 * S22;
    float v0 = T10 * S00 + T11 * S01 + T12 * S02;
    float v1 = T10 * S01 + T11 * S11 + T12 * S12;
    float v2 = T10 * S02 + T11 * S12 + T12 * S22;
    float c00 = u0 * T00 + u1 * T01 + u2 * T02;
    float c01 = u0 * T10 + u1 * T11 + u2 * T12;
    float c11 = v0 * T10 + v1 * T11 + v2 * T12;

    float a = c00 + 0.3f;
    float b = c01;
    float c = c11 + 0.3f;
    float det = a * c - b * b;
    bool pos_det = det > 0.f;
    float inv_det = pos_det ? 1.f / det : 0.f;
    float conA = c * inv_det, conB = -b * inv_det, conC = a * inv_det;
    float mid = 0.5f * (a + c);
    float lam = mid + sqrtf(fmaxf(mid * mid - det, 0.1f));
    bool visible = in_front && pos_det;
    float radii = visible ? ceilf(3.f * sqrtf(lam)) : 0.f;

    float opa = opacities[i];

    // outputs 1..3: radii, visibility_filter, means2D (all stored as float32)
    outp[3 * HW + i] = radii;
    outp[3 * HW + NG + i] = (radii > 0.f) ? 1.f : 0.f;
    outp[3 * HW + 2 * NG + i * 2 + 0] = gx;
    outp[3 * HW + 2 * NG + i * 2 + 1] = gy;

    float* p = params + i * PSTR;
    p[0] = gx;  p[1] = gy;  p[2] = radii; p[3] = visible ? opa : 0.f;
    p[4] = conA; p[5] = conB; p[6] = conC;
    p[7] = cr;  p[8] = cg;  p[9] = cb;  p[10] = 0.f; p[11] = 0.f;

    keys[i] = visible ? depth : 1e30f;   // matches argsort(where(visible, depth, inf))
}

// ---------------------------------------------------------------------------
// Kernel 2: stable rank-by-counting sort (one block per gaussian, wave reduce)
// ---------------------------------------------------------------------------
__global__ __launch_bounds__(64) void sort_kernel(
    const float* __restrict__ keys, const float* __restrict__ params,
    float* __restrict__ sorted)
{
    const int i = blockIdx.x;       // gaussian index
    const int lane = threadIdx.x;
    const float ki = keys[i];
    int cnt = 0;
#pragma unroll
    for (int k = 0; k < NG / 64; ++k) {
        int j = lane + k * 64;
        float kj = keys[j];
        // stable: strictly-less OR equal-with-smaller-index goes first
        cnt += (kj < ki || (kj == ki && j < i)) ? 1 : 0;
    }
    for (int off = 32; off > 0; off >>= 1) cnt += __shfl_down(cnt, off);
    int rank = __shfl(cnt, 0);
    if (lane < PSTR) sorted[rank * PSTR + lane] = params[i * PSTR + lane];
}

// ---------------------------------------------------------------------------
// Kernel 3: rasterize. One wave = one 8x8 pixel tile; sorted params in LDS.
// ---------------------------------------------------------------------------
__global__ __launch_bounds__(64) void raster_kernel(
    const float* __restrict__ sorted, const float* __restrict__ bg,
    float* __restrict__ outp)
{
    __shared__ float sp[NG * PSTR];   // 48 KB
    const int t = threadIdx.x;
    {
        const float4* src = (const float4*)sorted;
        float4* dst = (float4*)sp;
        for (int k = t; k < NG * PSTR / 4; k += 64) dst[k] = src[k];
    }
    __syncthreads();

    const int tilesX = W_IMG / 8;
    const int tileX = blockIdx.x % tilesX;
    const int tileY = blockIdx.x / tilesX;
    const int lx = t & 7, ly = t >> 3;
    const int pxi = tileX * 8 + lx;
    const int pyi = tileY * 8 + ly;
    const float px = (float)pxi, py = (float)pyi;

    float T = 1.f, accR = 0.f, accG = 0.f, accB = 0.f;

    for (int j = 0; j < NG; ++j) {
        const float* p = sp + j * PSTR;
        float gx = p[0], gy = p[1], rad = p[2];
        float dx = gx - px, dy = gy - py;
        bool cover = (fabsf(dx) <= rad) && (fabsf(dy) <= rad);
        if (__any(cover)) {
            float opa = p[3], A = p[4], Bc = p[5], Cc = p[6];
            float power = -0.5f * (A * dx * dx + Cc * dy * dy) - Bc * dx * dy;
            float alpha = fminf(0.99f, opa * __expf(fminf(power, 0.f)));
            bool keep = cover && (power <= 0.f) && (alpha >= (1.f / 255.f));
            alpha = keep ? alpha : 0.f;
            float w = alpha * T;
            accR += w * p[7];
            accG += w * p[8];
            accB += w * p[9];
            T *= (1.f - alpha);
        }
    }

    const int pix = pyi * W_IMG + pxi;
    outp[pix]          = accR + T * bg[0];
    outp[HW + pix]     = accG + T * bg[1];
    outp[2 * HW + pix] = accB + T * bg[2];
}

// ---------------------------------------------------------------------------
extern "C" void kernel_launch(void* const* d_in, const int* in_sizes, int n_in,
                              void* d_out, int out_size, void* d_ws, size_t ws_size,
                              hipStream_t stream)
{
    const float* means3D   = (const float*)d_in[0];
    const float* scales    = (const float*)d_in[1];
    const float* rotations = (const float*)d_in[2];
    const float* opacities = (const float*)d_in[3];
    const float* shs       = (const float*)d_in[4];
    const float* viewm     = (const float*)d_in[5];
    const float* projm     = (const float*)d_in[6];
    const float* campos    = (const float*)d_in[7];
    const float* bg        = (const float*)d_in[8];
    // d_in[9] / d_in[10] are image_height / image_width (fixed 192 — hard-coded)

    float* outp   = (float*)d_out;
    float* params = (float*)d_ws;                 // NG*PSTR floats
    float* sorted = params + NG * PSTR;           // NG*PSTR floats
    float* keys   = sorted + NG * PSTR;           // NG floats

    preprocess_kernel<<<NG / 64, 64, 0, stream>>>(
        means3D, scales, rotations, opacities, shs, viewm, projm, campos,
        params, keys, outp);

    sort_kernel<<<NG, 64, 0, stream>>>(keys, params, sorted);

    raster_kernel<<<(W_IMG / 8) * (H_IMG / 8), 64, 0, stream>>>(sorted, bg, outp);
}

// Round 2
// 93.777 us; speedup vs baseline: 1.7090x; 1.7090x over previous
//
#include <hip/hip_runtime.h>

#define NG      1024
#define W_IMG   192
#define H_IMG   192
#define HW      (W_IMG * H_IMG)
#define PSTR    12          // floats per gaussian record (3 x float4)
#define NSEG    8
#define SEGLEN  (NG / NSEG) // 128
#define TILES_X (W_IMG / 8) // 24
#define TILES_Y (H_IMG / 8) // 24
#define NTILES  (TILES_X * TILES_Y)  // 576

// record: [gx, gy, radii, opa][conA, conB, conC, 0][r, g, b, 0]

// ---------------------------------------------------------------------------
// Kernel 1: per-gaussian preprocess
// ---------------------------------------------------------------------------
__global__ __launch_bounds__(64) void preprocess_kernel(
    const float* __restrict__ means3D, const float* __restrict__ scales,
    const float* __restrict__ rotations, const float* __restrict__ opacities,
    const float* __restrict__ shs, const float* __restrict__ viewm,
    const float* __restrict__ projm, const float* __restrict__ campos,
    float* __restrict__ params, float* __restrict__ keys,
    float* __restrict__ outp)
{
    const int i = blockIdx.x * 64 + threadIdx.x;
    if (i >= NG) return;

    const float mx = means3D[i * 3 + 0];
    const float my = means3D[i * 3 + 1];
    const float mz = means3D[i * 3 + 2];

    // ---- SH degree-3 color ----
    float dxc = mx - campos[0], dyc = my - campos[1], dzc = mz - campos[2];
    float nrm = sqrtf(dxc * dxc + dyc * dyc + dzc * dzc);
    float x = dxc / nrm, y = dyc / nrm, z = dzc / nrm;
    float xx = x * x, yy = y * y, zz = z * z;
    float xy = x * y, yz = y * z, xz = x * z;

    float basis[16];
    basis[0]  = 0.28209479177387814f;
    basis[1]  = -0.4886025119029199f * y;
    basis[2]  =  0.4886025119029199f * z;
    basis[3]  = -0.4886025119029199f * x;
    basis[4]  =  1.0925484305920792f * xy;
    basis[5]  = -1.0925484305920792f * yz;
    basis[6]  =  0.31539156525252005f * (2.f * zz - xx - yy);
    basis[7]  = -1.0925484305920792f * xz;
    basis[8]  =  0.5462742152960396f * (xx - yy);
    basis[9]  = -0.5900435899266435f * y * (3.f * xx - yy);
    basis[10] =  2.890611442640554f  * xy * z;
    basis[11] = -0.4570457994644658f * y * (4.f * zz - xx - yy);
    basis[12] =  0.3731763325901154f * z * (2.f * zz - 3.f * xx - 3.f * yy);
    basis[13] = -0.4570457994644658f * x * (4.f * zz - xx - yy);
    basis[14] =  1.445305721320277f  * z * (xx - yy);
    basis[15] = -0.5900435899266435f * x * (xx - yy - 3.f * zz);

    float cr = 0.f, cg = 0.f, cb = 0.f;
#pragma unroll
    for (int k = 0; k < 16; ++k) {
        float b = basis[k];
        cr += b * shs[(i * 16 + k) * 3 + 0];
        cg += b * shs[(i * 16 + k) * 3 + 1];
        cb += b * shs[(i * 16 + k) * 3 + 2];
    }
    cr = fmaxf(cr + 0.5f, 0.f);
    cg = fmaxf(cg + 0.5f, 0.f);
    cb = fmaxf(cb + 0.5f, 0.f);

    // ---- cov3d = (R*S)(R*S)^T ----
    float qr = rotations[i * 4 + 0], qx = rotations[i * 4 + 1];
    float qy = rotations[i * 4 + 2], qz = rotations[i * 4 + 3];
    float sx = scales[i * 3 + 0], sy = scales[i * 3 + 1], sz = scales[i * 3 + 2];
    float R00 = 1.f - 2.f * (qy * qy + qz * qz), R01 = 2.f * (qx * qy - qr * qz), R02 = 2.f * (qx * qz + qr * qy);
    float R10 = 2.f * (qx * qy + qr * qz), R11 = 1.f - 2.f * (qx * qx + qz * qz), R12 = 2.f * (qy * qz - qr * qx);
    float R20 = 2.f * (qx * qz - qr * qy), R21 = 2.f * (qy * qz + qr * qx), R22 = 1.f - 2.f * (qx * qx + qy * qy);
    float M00 = R00 * sx, M01 = R01 * sy, M02 = R02 * sz;
    float M10 = R10 * sx, M11 = R11 * sy, M12 = R12 * sz;
    float M20 = R20 * sx, M21 = R21 * sy, M22 = R22 * sz;
    float S00 = M00 * M00 + M01 * M01 + M02 * M02;
    float S01 = M00 * M10 + M01 * M11 + M02 * M12;
    float S02 = M00 * M20 + M01 * M21 + M02 * M22;
    float S11 = M10 * M10 + M11 * M11 + M12 * M12;
    float S12 = M10 * M20 + M11 * M21 + M12 * M22;
    float S22 = M20 * M20 + M21 * M21 + M22 * M22;

    // ---- view / proj transform ----
    float pv0 = viewm[0] * mx + viewm[1] * my + viewm[2]  * mz + viewm[3];
    float pv1 = viewm[4] * mx + viewm[5] * my + viewm[6]  * mz + viewm[7];
    float pv2 = viewm[8] * mx + viewm[9] * my + viewm[10] * mz + viewm[11];
    float ph0 = projm[0]  * mx + projm[1]  * my + projm[2]  * mz + projm[3];
    float ph1 = projm[4]  * mx + projm[5]  * my + projm[6]  * mz + projm[7];
    float ph3 = projm[12] * mx + projm[13] * my + projm[14] * mz + projm[15];
    float pp0 = ph0 / (ph3 + 1e-7f);
    float pp1 = ph1 / (ph3 + 1e-7f);
    float gx = ((pp0 + 1.f) * (float)W_IMG - 1.f) * 0.5f;
    float gy = ((pp1 + 1.f) * (float)H_IMG - 1.f) * 0.5f;

    float depth = pv2;
    bool in_front = depth > 0.2f;
    float tz = in_front ? depth : 1.f;
    const float lim = 1.3f * 0.5f;   // 1.3 * TANFOV
    float txv = fminf(fmaxf(pv0 / tz, -lim), lim) * tz;
    float tyv = fminf(fmaxf(pv1 / tz, -lim), lim) * tz;
    const float fx = (float)W_IMG / (2.f * 0.5f);
    const float fy = (float)H_IMG / (2.f * 0.5f);
    float J00 = fx / tz, J02 = -fx * txv / (tz * tz);
    float J11 = fy / tz, J12 = -fy * tyv / (tz * tz);

    float T00 = J00 * viewm[0] + J02 * viewm[8];
    float T01 = J00 * viewm[1] + J02 * viewm[9];
    float T02 = J00 * viewm[2] + J02 * viewm[10];
    float T10 = J11 * viewm[4] + J12 * viewm[8];
    float T11 = J11 * viewm[5] + J12 * viewm[9];
    float T12 = J11 * viewm[6] + J12 * viewm[10];

    float u0 = T00 * S00 + T01 * S01 + T02 * S02;
    float u1 = T00 * S01 + T01 * S11 + T02 * S12;
    float u2 = T00 * S02 + T01 * S12 + T02 * S22;
    float v0 = T10 * S00 + T11 * S01 + T12 * S02;
    float v1 = T10 * S01 + T11 * S11 + T12 * S12;
    float v2 = T10 * S02 + T11 * S12 + T12 * S22;
    float c00 = u0 * T00 + u1 * T01 + u2 * T02;
    float c01 = u0 * T10 + u1 * T11 + u2 * T12;
    float c11 = v0 * T10 + v1 * T11 + v2 * T12;

    float a = c00 + 0.3f;
    float b = c01;
    float c = c11 + 0.3f;
    float det = a * c - b * b;
    bool pos_det = det > 0.f;
    float inv_det = pos_det ? 1.f / det : 0.f;
    float conA = c * inv_det, conB = -b * inv_det, conC = a * inv_det;
    float mid = 0.5f * (a + c);
    float lam = mid + sqrtf(fmaxf(mid * mid - det, 0.1f));
    bool visible = in_front && pos_det;
    float radii = visible ? ceilf(3.f * sqrtf(lam)) : 0.f;

    float opa = opacities[i];

    outp[3 * HW + i] = radii;
    outp[3 * HW + NG + i] = (radii > 0.f) ? 1.f : 0.f;
    outp[3 * HW + 2 * NG + i * 2 + 0] = gx;
    outp[3 * HW + 2 * NG + i * 2 + 1] = gy;

    float* p = params + i * PSTR;
    p[0] = gx;   p[1] = gy;   p[2]  = radii; p[3]  = visible ? opa : 0.f;
    p[4] = conA; p[5] = conB; p[6]  = conC;  p[7]  = 0.f;
    p[8] = cr;   p[9] = cg;   p[10] = cb;    p[11] = 0.f;

    keys[i] = visible ? depth : 1e30f;
}

// ---------------------------------------------------------------------------
// Kernel 2: stable rank-by-counting sort (one block per gaussian, wave reduce)
// ---------------------------------------------------------------------------
__global__ __launch_bounds__(64) void sort_kernel(
    const float* __restrict__ keys, const float* __restrict__ params,
    float* __restrict__ sorted)
{
    const int i = blockIdx.x;
    const int lane = threadIdx.x;
    const float ki = keys[i];
    int cnt = 0;
#pragma unroll
    for (int k = 0; k < NG / 64; ++k) {
        int j = lane + k * 64;
        float kj = keys[j];
        cnt += (kj < ki || (kj == ki && j < i)) ? 1 : 0;
    }
    for (int off = 32; off > 0; off >>= 1) cnt += __shfl_down(cnt, off);
    int rank = __shfl(cnt, 0);
    if (lane < PSTR) sorted[rank * PSTR + lane] = params[i * PSTR + lane];
}

// ---------------------------------------------------------------------------
// Kernel 3: segmented rasterize. Block = 256 threads = 4 waves.
// Wave w handles tile (tg*4 + w) for segment seg; one 6 KB LDS stage shared.
// Each wave composites its 128-gaussian segment over its 8x8 pixel tile and
// writes (R,G,B,T) to segbuf[seg][pix].
// ---------------------------------------------------------------------------
__global__ __launch_bounds__(256) void raster_seg_kernel(
    const float* __restrict__ sorted, float4* __restrict__ segbuf)
{
    __shared__ float4 sp[SEGLEN * 3];   // 6 KB
    const int t = threadIdx.x;
    const int tg  = blockIdx.x % (NTILES / 4);
    const int seg = blockIdx.x / (NTILES / 4);

    {
        const float4* src = (const float4*)(sorted + seg * SEGLEN * PSTR);
        for (int k = t; k < SEGLEN * 3; k += 256) sp[k] = src[k];
    }
    __syncthreads();

    const int wave = t >> 6;
    const int lane = t & 63;
    const int tileIdx = tg * 4 + wave;
    const int tileX = tileIdx % TILES_X;
    const int tileY = tileIdx / TILES_X;
    const int lx = lane & 7, ly = lane >> 3;
    const int pxi = tileX * 8 + lx;
    const int pyi = tileY * 8 + ly;
    const float px = (float)pxi, py = (float)pyi;

    float T = 1.f, accR = 0.f, accG = 0.f, accB = 0.f;

    for (int j = 0; j < SEGLEN; ++j) {
        float4 g0 = sp[j * 3 + 0];          // gx, gy, rad, opa
        float dx = g0.x - px, dy = g0.y - py;
        bool cover = (fabsf(dx) <= g0.z) && (fabsf(dy) <= g0.z);
        if (__any(cover)) {
            float4 g1 = sp[j * 3 + 1];      // conA, conB, conC, -
            float power = -0.5f * (g1.x * dx * dx + g1.z * dy * dy) - g1.y * dx * dy;
            float alpha = fminf(0.99f, g0.w * __expf(fminf(power, 0.f)));
            bool keep = cover && (power <= 0.f) && (alpha >= (1.f / 255.f));
            alpha = keep ? alpha : 0.f;
            float w = alpha * T;
            float4 g2 = sp[j * 3 + 2];      // r, g, b, -
            accR += w * g2.x;
            accG += w * g2.y;
            accB += w * g2.z;
            T *= (1.f - alpha);
        }
    }

    const int pix = pyi * W_IMG + pxi;
    segbuf[seg * HW + pix] = make_float4(accR, accG, accB, T);
}

// ---------------------------------------------------------------------------
// Kernel 4: combine the NSEG segment layers front-to-back + background
// ---------------------------------------------------------------------------
__global__ __launch_bounds__(256) void combine_kernel(
    const float4* __restrict__ segbuf, const float* __restrict__ bg,
    float* __restrict__ outp)
{
    const int pix = blockIdx.x * 256 + threadIdx.x;
    if (pix >= HW) return;
    float T = 1.f, r = 0.f, g = 0.f, b = 0.f;
#pragma unroll
    for (int s = 0; s < NSEG; ++s) {
        float4 c = segbuf[s * HW + pix];
        r += T * c.x;
        g += T * c.y;
        b += T * c.z;
        T *= c.w;
    }
    outp[pix]          = r + T * bg[0];
    outp[HW + pix]     = g + T * bg[1];
    outp[2 * HW + pix] = b + T * bg[2];
}

// ---------------------------------------------------------------------------
extern "C" void kernel_launch(void* const* d_in, const int* in_sizes, int n_in,
                              void* d_out, int out_size, void* d_ws, size_t ws_size,
                              hipStream_t stream)
{
    const float* means3D   = (const float*)d_in[0];
    const float* scales    = (const float*)d_in[1];
    const float* rotations = (const float*)d_in[2];
    const float* opacities = (const float*)d_in[3];
    const float* shs       = (const float*)d_in[4];
    const float* viewm     = (const float*)d_in[5];
    const float* projm     = (const float*)d_in[6];
    const float* campos    = (const float*)d_in[7];
    const float* bg        = (const float*)d_in[8];

    float* outp   = (float*)d_out;
    float* params = (float*)d_ws;                 // NG*PSTR floats
    float* sorted = params + NG * PSTR;           // NG*PSTR floats
    float* keys   = sorted + NG * PSTR;           // NG floats
    float4* segbuf = (float4*)(keys + NG);        // NSEG*HW float4 (4.5 MB)

    preprocess_kernel<<<NG / 64, 64, 0, stream>>>(
        means3D, scales, rotations, opacities, shs, viewm, projm, campos,
        params, keys, outp);

    sort_kernel<<<NG, 64, 0, stream>>>(keys, params, sorted);

    raster_seg_kernel<<<(NTILES / 4) * NSEG, 256, 0, stream>>>(sorted, segbuf);

    combine_kernel<<<(HW + 255) / 256, 256, 0, stream>>>(segbuf, bg, outp);
}

// Round 3
// 85.175 us; speedup vs baseline: 1.8816x; 1.1010x over previous
//
#include <hip/hip_runtime.h>

#define NG      1024
#define W_IMG   192
#define H_IMG   192
#define HW      (W_IMG * H_IMG)
#define PSTR    12          // floats per gaussian record (3 x float4)
#define NSEG    8
#define SEGLEN  (NG / NSEG) // 128
#define TILES_X (W_IMG / 8) // 24
#define TILES_Y (H_IMG / 8) // 24
#define NTILES  (TILES_X * TILES_Y)  // 576

// record: [gx, gy, radii, opa][conA, conB, conC, 0][r, g, b, 0]

// ---------------------------------------------------------------------------
// Kernel 1: per-gaussian preprocess
// ---------------------------------------------------------------------------
__global__ __launch_bounds__(64) void preprocess_kernel(
    const float* __restrict__ means3D, const float* __restrict__ scales,
    const float* __restrict__ rotations, const float* __restrict__ opacities,
    const float* __restrict__ shs, const float* __restrict__ viewm,
    const float* __restrict__ projm, const float* __restrict__ campos,
    float* __restrict__ params, float* __restrict__ keys,
    float* __restrict__ outp)
{
    const int i = blockIdx.x * 64 + threadIdx.x;
    if (i >= NG) return;

    const float mx = means3D[i * 3 + 0];
    const float my = means3D[i * 3 + 1];
    const float mz = means3D[i * 3 + 2];

    // ---- SH degree-3 color ----
    float dxc = mx - campos[0], dyc = my - campos[1], dzc = mz - campos[2];
    float nrm = sqrtf(dxc * dxc + dyc * dyc + dzc * dzc);
    float x = dxc / nrm, y = dyc / nrm, z = dzc / nrm;
    float xx = x * x, yy = y * y, zz = z * z;
    float xy = x * y, yz = y * z, xz = x * z;

    float basis[16];
    basis[0]  = 0.28209479177387814f;
    basis[1]  = -0.4886025119029199f * y;
    basis[2]  =  0.4886025119029199f * z;
    basis[3]  = -0.4886025119029199f * x;
    basis[4]  =  1.0925484305920792f * xy;
    basis[5]  = -1.0925484305920792f * yz;
    basis[6]  =  0.31539156525252005f * (2.f * zz - xx - yy);
    basis[7]  = -1.0925484305920792f * xz;
    basis[8]  =  0.5462742152960396f * (xx - yy);
    basis[9]  = -0.5900435899266435f * y * (3.f * xx - yy);
    basis[10] =  2.890611442640554f  * xy * z;
    basis[11] = -0.4570457994644658f * y * (4.f * zz - xx - yy);
    basis[12] =  0.3731763325901154f * z * (2.f * zz - 3.f * xx - 3.f * yy);
    basis[13] = -0.4570457994644658f * x * (4.f * zz - xx - yy);
    basis[14] =  1.445305721320277f  * z * (xx - yy);
    basis[15] = -0.5900435899266435f * x * (xx - yy - 3.f * zz);

    float cr = 0.f, cg = 0.f, cb = 0.f;
#pragma unroll
    for (int k = 0; k < 16; ++k) {
        float b = basis[k];
        cr += b * shs[(i * 16 + k) * 3 + 0];
        cg += b * shs[(i * 16 + k) * 3 + 1];
        cb += b * shs[(i * 16 + k) * 3 + 2];
    }
    cr = fmaxf(cr + 0.5f, 0.f);
    cg = fmaxf(cg + 0.5f, 0.f);
    cb = fmaxf(cb + 0.5f, 0.f);

    // ---- cov3d = (R*S)(R*S)^T ----
    float qr = rotations[i * 4 + 0], qx = rotations[i * 4 + 1];
    float qy = rotations[i * 4 + 2], qz = rotations[i * 4 + 3];
    float sx = scales[i * 3 + 0], sy = scales[i * 3 + 1], sz = scales[i * 3 + 2];
    float R00 = 1.f - 2.f * (qy * qy + qz * qz), R01 = 2.f * (qx * qy - qr * qz), R02 = 2.f * (qx * qz + qr * qy);
    float R10 = 2.f * (qx * qy + qr * qz), R11 = 1.f - 2.f * (qx * qx + qz * qz), R12 = 2.f * (qy * qz - qr * qx);
    float R20 = 2.f * (qx * qz - qr * qy), R21 = 2.f * (qy * qz + qr * qx), R22 = 1.f - 2.f * (qx * qx + qy * qy);
    float M00 = R00 * sx, M01 = R01 * sy, M02 = R02 * sz;
    float M10 = R10 * sx, M11 = R11 * sy, M12 = R12 * sz;
    float M20 = R20 * sx, M21 = R21 * sy, M22 = R22 * sz;
    float S00 = M00 * M00 + M01 * M01 + M02 * M02;
    float S01 = M00 * M10 + M01 * M11 + M02 * M12;
    float S02 = M00 * M20 + M01 * M21 + M02 * M22;
    float S11 = M10 * M10 + M11 * M11 + M12 * M12;
    float S12 = M10 * M20 + M11 * M21 + M12 * M22;
    float S22 = M20 * M20 + M21 * M21 + M22 * M22;

    // ---- view / proj transform ----
    float pv0 = viewm[0] * mx + viewm[1] * my + viewm[2]  * mz + viewm[3];
    float pv1 = viewm[4] * mx + viewm[5] * my + viewm[6]  * mz + viewm[7];
    float pv2 = viewm[8] * mx + viewm[9] * my + viewm[10] * mz + viewm[11];
    float ph0 = projm[0]  * mx + projm[1]  * my + projm[2]  * mz + projm[3];
    float ph1 = projm[4]  * mx + projm[5]  * my + projm[6]  * mz + projm[7];
    float ph3 = projm[12] * mx + projm[13] * my + projm[14] * mz + projm[15];
    float pp0 = ph0 / (ph3 + 1e-7f);
    float pp1 = ph1 / (ph3 + 1e-7f);
    float gx = ((pp0 + 1.f) * (float)W_IMG - 1.f) * 0.5f;
    float gy = ((pp1 + 1.f) * (float)H_IMG - 1.f) * 0.5f;

    float depth = pv2;
    bool in_front = depth > 0.2f;
    float tz = in_front ? depth : 1.f;
    const float lim = 1.3f * 0.5f;   // 1.3 * TANFOV
    float txv = fminf(fmaxf(pv0 / tz, -lim), lim) * tz;
    float tyv = fminf(fmaxf(pv1 / tz, -lim), lim) * tz;
    const float fx = (float)W_IMG / (2.f * 0.5f);
    const float fy = (float)H_IMG / (2.f * 0.5f);
    float J00 = fx / tz, J02 = -fx * txv / (tz * tz);
    float J11 = fy / tz, J12 = -fy * tyv / (tz * tz);

    float T00 = J00 * viewm[0] + J02 * viewm[8];
    float T01 = J00 * viewm[1] + J02 * viewm[9];
    float T02 = J00 * viewm[2] + J02 * viewm[10];
    float T10 = J11 * viewm[4] + J12 * viewm[8];
    float T11 = J11 * viewm[5] + J12 * viewm[9];
    float T12 = J11 * viewm[6] + J12 * viewm[10];

    float u0 = T00 * S00 + T01 * S01 + T02 * S02;
    float u1 = T00 * S01 + T01 * S11 + T02 * S12;
    float u2 = T00 * S02 + T01 * S12 + T02 * S22;
    float v0 = T10 * S00 + T11 * S01 + T12 * S02;
    float v1 = T10 * S01 + T11 * S11 + T12 * S12;
    float v2 = T10 * S02 + T11 * S12 + T12 * S22;
    float c00 = u0 * T00 + u1 * T01 + u2 * T02;
    float c01 = u0 * T10 + u1 * T11 + u2 * T12;
    float c11 = v0 * T10 + v1 * T11 + v2 * T12;

    float a = c00 + 0.3f;
    float b = c01;
    float c = c11 + 0.3f;
    float det = a * c - b * b;
    bool pos_det = det > 0.f;
    float inv_det = pos_det ? 1.f / det : 0.f;
    float conA = c * inv_det, conB = -b * inv_det, conC = a * inv_det;
    float mid = 0.5f * (a + c);
    float lam = mid + sqrtf(fmaxf(mid * mid - det, 0.1f));
    bool visible = in_front && pos_det;
    float radii = visible ? ceilf(3.f * sqrtf(lam)) : 0.f;

    float opa = opacities[i];

    outp[3 * HW + i] = radii;
    outp[3 * HW + NG + i] = (radii > 0.f) ? 1.f : 0.f;
    outp[3 * HW + 2 * NG + i * 2 + 0] = gx;
    outp[3 * HW + 2 * NG + i * 2 + 1] = gy;

    float* p = params + i * PSTR;
    p[0] = gx;   p[1] = gy;   p[2]  = radii; p[3]  = visible ? opa : 0.f;
    p[4] = conA; p[5] = conB; p[6]  = conC;  p[7]  = 0.f;
    p[8] = cr;   p[9] = cg;   p[10] = cb;    p[11] = 0.f;

    keys[i] = visible ? depth : 1e30f;
}

// ---------------------------------------------------------------------------
// Kernel 2: stable rank-by-counting sort (one block per gaussian, wave reduce)
// ---------------------------------------------------------------------------
__global__ __launch_bounds__(64) void sort_kernel(
    const float* __restrict__ keys, const float* __restrict__ params,
    float* __restrict__ sorted)
{
    const int i = blockIdx.x;
    const int lane = threadIdx.x;
    const float ki = keys[i];
    int cnt = 0;
#pragma unroll
    for (int k = 0; k < NG / 64; ++k) {
        int j = lane + k * 64;
        float kj = keys[j];
        cnt += (kj < ki || (kj == ki && j < i)) ? 1 : 0;
    }
    for (int off = 32; off > 0; off >>= 1) cnt += __shfl_down(cnt, off);
    int rank = __shfl(cnt, 0);
    if (lane < PSTR) sorted[rank * PSTR + lane] = params[i * PSTR + lane];
}

// ---------------------------------------------------------------------------
// Kernel 3: fused rasterize + combine. One block = one 8x8 tile = 512 threads
// = 8 waves; wave w composites segment w (128 gaussians) using wave-parallel
// bbox culling (2 ballot rounds) then an ordered set-bit loop over survivors.
// Segment partials combine through 8 KB of LDS; no global segbuf, no 4th
// kernel.
// ---------------------------------------------------------------------------
__global__ __launch_bounds__(512) void raster_kernel(
    const float* __restrict__ sorted, const float* __restrict__ bg,
    float* __restrict__ outp)
{
    __shared__ float4 sp[NG * 3];          // 48 KB: all sorted records
    __shared__ float4 segacc[NSEG * 64];   // 8 KB: per-segment (R,G,B,T)

    const int t = threadIdx.x;
    {
        const float4* src = (const float4*)sorted;
        for (int k = t; k < NG * 3; k += 512) sp[k] = src[k];
    }
    __syncthreads();

    const int wave = t >> 6;        // segment index 0..7
    const int lane = t & 63;
    const int tileX = blockIdx.x % TILES_X;
    const int tileY = blockIdx.x / TILES_X;
    const int lx = lane & 7, ly = lane >> 3;
    const int pxi = tileX * 8 + lx;
    const int pyi = tileY * 8 + ly;
    const float px = (float)pxi, py = (float)pyi;
    const float tx0 = (float)(tileX * 8);
    const float ty0 = (float)(tileY * 8);

    const int base = wave * SEGLEN;

    // wave-parallel conservative cull: lane tests gaussian base+h*64+lane
    // against the whole tile rect (superset of any per-pixel cover).
    unsigned long long m[2];
#pragma unroll
    for (int h = 0; h < 2; ++h) {
        float4 g0 = sp[(base + h * 64 + lane) * 3];
        bool hit = (g0.x >= tx0 - g0.z) && (g0.x <= tx0 + 7.f + g0.z) &&
                   (g0.y >= ty0 - g0.z) && (g0.y <= ty0 + 7.f + g0.z);
        m[h] = __ballot(hit);
    }

    float T = 1.f, accR = 0.f, accG = 0.f, accB = 0.f;
#pragma unroll
    for (int h = 0; h < 2; ++h) {
        unsigned long long mask = m[h];
        while (mask) {                       // wave-uniform: mask is ballot
            const int j = __ffsll(mask) - 1; // lowest set bit = nearest depth
            mask &= mask - 1;
            const int gi = base + h * 64 + j;
            float4 g0 = sp[gi * 3 + 0];      // broadcast reads, conflict-free
            float4 g1 = sp[gi * 3 + 1];
            float4 g2 = sp[gi * 3 + 2];
            float dx = g0.x - px, dy = g0.y - py;
            bool cover = (fabsf(dx) <= g0.z) && (fabsf(dy) <= g0.z);
            float power = -0.5f * (g1.x * dx * dx + g1.z * dy * dy) - g1.y * dx * dy;
            float alpha = fminf(0.99f, g0.w * __expf(fminf(power, 0.f)));
            bool keep = cover && (power <= 0.f) && (alpha >= (1.f / 255.f));
            alpha = keep ? alpha : 0.f;
            float w = alpha * T;
            accR += w * g2.x;
            accG += w * g2.y;
            accB += w * g2.z;
            T *= (1.f - alpha);
        }
    }

    segacc[wave * 64 + lane] = make_float4(accR, accG, accB, T);
    __syncthreads();

    // combine: first wave folds the 8 segment layers front-to-back
    if (t < 64) {
        float Tc = 1.f, r = 0.f, g = 0.f, b = 0.f;
#pragma unroll
        for (int s = 0; s < NSEG; ++s) {
            float4 cc = segacc[s * 64 + t];
            r += Tc * cc.x;
            g += Tc * cc.y;
            b += Tc * cc.z;
            Tc *= cc.w;
        }
        const int pix = pyi * W_IMG + pxi;   // t<64 -> lane==t, same pixel map
        outp[pix]          = r + Tc * bg[0];
        outp[HW + pix]     = g + Tc * bg[1];
        outp[2 * HW + pix] = b + Tc * bg[2];
    }
}

// ---------------------------------------------------------------------------
extern "C" void kernel_launch(void* const* d_in, const int* in_sizes, int n_in,
                              void* d_out, int out_size, void* d_ws, size_t ws_size,
                              hipStream_t stream)
{
    const float* means3D   = (const float*)d_in[0];
    const float* scales    = (const float*)d_in[1];
    const float* rotations = (const float*)d_in[2];
    const float* opacities = (const float*)d_in[3];
    const float* shs       = (const float*)d_in[4];
    const float* viewm     = (const float*)d_in[5];
    const float* projm     = (const float*)d_in[6];
    const float* campos    = (const float*)d_in[7];
    const float* bg        = (const float*)d_in[8];

    float* outp   = (float*)d_out;
    float* params = (float*)d_ws;                 // NG*PSTR floats
    float* sorted = params + NG * PSTR;           // NG*PSTR floats
    float* keys   = sorted + NG * PSTR;           // NG floats

    preprocess_kernel<<<NG / 64, 64, 0, stream>>>(
        means3D, scales, rotations, opacities, shs, viewm, projm, campos,
        params, keys, outp);

    sort_kernel<<<NG, 64, 0, stream>>>(keys, params, sorted);

    raster_kernel<<<NTILES, 512, 0, stream>>>(sorted, bg, outp);
}

// Round 4
// 83.659 us; speedup vs baseline: 1.9157x; 1.0181x over previous
//
#include <hip/hip_runtime.h>

#define NG      1024
#define W_IMG   192
#define H_IMG   192
#define HW      (W_IMG * H_IMG)
#define PSTR    12          // floats per gaussian record (3 x float4)
#define NSEG    8
#define TILES_X (W_IMG / 8) // 24
#define TILES_Y (H_IMG / 8) // 24
#define NTILES  (TILES_X * TILES_Y)  // 576

// record: [gx, gy, radii, opa][conA, conB, conC, depth][r, g, b, 0]

// ---------------------------------------------------------------------------
// Kernel 1: per-gaussian preprocess (also writes outputs 1..3)
// ---------------------------------------------------------------------------
__global__ __launch_bounds__(256) void preprocess_kernel(
    const float* __restrict__ means3D, const float* __restrict__ scales,
    const float* __restrict__ rotations, const float* __restrict__ opacities,
    const float* __restrict__ shs, const float* __restrict__ viewm,
    const float* __restrict__ projm, const float* __restrict__ campos,
    float* __restrict__ params, float* __restrict__ outp)
{
    const int i = blockIdx.x * 256 + threadIdx.x;
    if (i >= NG) return;

    const float mx = means3D[i * 3 + 0];
    const float my = means3D[i * 3 + 1];
    const float mz = means3D[i * 3 + 2];

    // ---- SH degree-3 color ----
    float dxc = mx - campos[0], dyc = my - campos[1], dzc = mz - campos[2];
    float nrm = sqrtf(dxc * dxc + dyc * dyc + dzc * dzc);
    float x = dxc / nrm, y = dyc / nrm, z = dzc / nrm;
    float xx = x * x, yy = y * y, zz = z * z;
    float xy = x * y, yz = y * z, xz = x * z;

    float basis[16];
    basis[0]  = 0.28209479177387814f;
    basis[1]  = -0.4886025119029199f * y;
    basis[2]  =  0.4886025119029199f * z;
    basis[3]  = -0.4886025119029199f * x;
    basis[4]  =  1.0925484305920792f * xy;
    basis[5]  = -1.0925484305920792f * yz;
    basis[6]  =  0.31539156525252005f * (2.f * zz - xx - yy);
    basis[7]  = -1.0925484305920792f * xz;
    basis[8]  =  0.5462742152960396f * (xx - yy);
    basis[9]  = -0.5900435899266435f * y * (3.f * xx - yy);
    basis[10] =  2.890611442640554f  * xy * z;
    basis[11] = -0.4570457994644658f * y * (4.f * zz - xx - yy);
    basis[12] =  0.3731763325901154f * z * (2.f * zz - 3.f * xx - 3.f * yy);
    basis[13] = -0.4570457994644658f * x * (4.f * zz - xx - yy);
    basis[14] =  1.445305721320277f  * z * (xx - yy);
    basis[15] = -0.5900435899266435f * x * (xx - yy - 3.f * zz);

    float cr = 0.f, cg = 0.f, cb = 0.f;
#pragma unroll
    for (int k = 0; k < 16; ++k) {
        float b = basis[k];
        cr += b * shs[(i * 16 + k) * 3 + 0];
        cg += b * shs[(i * 16 + k) * 3 + 1];
        cb += b * shs[(i * 16 + k) * 3 + 2];
    }
    cr = fmaxf(cr + 0.5f, 0.f);
    cg = fmaxf(cg + 0.5f, 0.f);
    cb = fmaxf(cb + 0.5f, 0.f);

    // ---- cov3d = (R*S)(R*S)^T ----
    float qr = rotations[i * 4 + 0], qx = rotations[i * 4 + 1];
    float qy = rotations[i * 4 + 2], qz = rotations[i * 4 + 3];
    float sx = scales[i * 3 + 0], sy = scales[i * 3 + 1], sz = scales[i * 3 + 2];
    float R00 = 1.f - 2.f * (qy * qy + qz * qz), R01 = 2.f * (qx * qy - qr * qz), R02 = 2.f * (qx * qz + qr * qy);
    float R10 = 2.f * (qx * qy + qr * qz), R11 = 1.f - 2.f * (qx * qx + qz * qz), R12 = 2.f * (qy * qz - qr * qx);
    float R20 = 2.f * (qx * qz - qr * qy), R21 = 2.f * (qy * qz + qr * qx), R22 = 1.f - 2.f * (qx * qx + qy * qy);
    float M00 = R00 * sx, M01 = R01 * sy, M02 = R02 * sz;
    float M10 = R10 * sx, M11 = R11 * sy, M12 = R12 * sz;
    float M20 = R20 * sx, M21 = R21 * sy, M22 = R22 * sz;
    float S00 = M00 * M00 + M01 * M01 + M02 * M02;
    float S01 = M00 * M10 + M01 * M11 + M02 * M12;
    float S02 = M00 * M20 + M01 * M21 + M02 * M22;
    float S11 = M10 * M10 + M11 * M11 + M12 * M12;
    float S12 = M10 * M20 + M11 * M21 + M12 * M22;
    float S22 = M20 * M20 + M21 * M21 + M22 * M22;

    // ---- view / proj transform ----
    float pv0 = viewm[0] * mx + viewm[1] * my + viewm[2]  * mz + viewm[3];
    float pv1 = viewm[4] * mx + viewm[5] * my + viewm[6]  * mz + viewm[7];
    float pv2 = viewm[8] * mx + viewm[9] * my + viewm[10] * mz + viewm[11];
    float ph0 = projm[0]  * mx + projm[1]  * my + projm[2]  * mz + projm[3];
    float ph1 = projm[4]  * mx + projm[5]  * my + projm[6]  * mz + projm[7];
    float ph3 = projm[12] * mx + projm[13] * my + projm[14] * mz + projm[15];
    float pp0 = ph0 / (ph3 + 1e-7f);
    float pp1 = ph1 / (ph3 + 1e-7f);
    float gx = ((pp0 + 1.f) * (float)W_IMG - 1.f) * 0.5f;
    float gy = ((pp1 + 1.f) * (float)H_IMG - 1.f) * 0.5f;

    float depth = pv2;
    bool in_front = depth > 0.2f;
    float tz = in_front ? depth : 1.f;
    const float lim = 1.3f * 0.5f;   // 1.3 * TANFOV
    float txv = fminf(fmaxf(pv0 / tz, -lim), lim) * tz;
    float tyv = fminf(fmaxf(pv1 / tz, -lim), lim) * tz;
    const float fx = (float)W_IMG / (2.f * 0.5f);
    const float fy = (float)H_IMG / (2.f * 0.5f);
    float J00 = fx / tz, J02 = -fx * txv / (tz * tz);
    float J11 = fy / tz, J12 = -fy * tyv / (tz * tz);

    float T00 = J00 * viewm[0] + J02 * viewm[8];
    float T01 = J00 * viewm[1] + J02 * viewm[9];
    float T02 = J00 * viewm[2] + J02 * viewm[10];
    float T10 = J11 * viewm[4] + J12 * viewm[8];
    float T11 = J11 * viewm[5] + J12 * viewm[9];
    float T12 = J11 * viewm[6] + J12 * viewm[10];

    float u0 = T00 * S00 + T01 * S01 + T02 * S02;
    float u1 = T00 * S01 + T01 * S11 + T02 * S12;
    float u2 = T00 * S02 + T01 * S12 + T02 * S22;
    float v0 = T10 * S00 + T11 * S01 + T12 * S02;
    float v1 = T10 * S01 + T11 * S11 + T12 * S12;
    float v2 = T10 * S02 + T11 * S12 + T12 * S22;
    float c00 = u0 * T00 + u1 * T01 + u2 * T02;
    float c01 = u0 * T10 + u1 * T11 + u2 * T12;
    float c11 = v0 * T10 + v1 * T11 + v2 * T12;

    float a = c00 + 0.3f;
    float b = c01;
    float c = c11 + 0.3f;
    float det = a * c - b * b;
    bool pos_det = det > 0.f;
    float inv_det = pos_det ? 1.f / det : 0.f;
    float conA = c * inv_det, conB = -b * inv_det, conC = a * inv_det;
    float mid = 0.5f * (a + c);
    float lam = mid + sqrtf(fmaxf(mid * mid - det, 0.1f));
    bool visible = in_front && pos_det;
    float radii = visible ? ceilf(3.f * sqrtf(lam)) : 0.f;

    float opa = opacities[i];

    outp[3 * HW + i] = radii;
    outp[3 * HW + NG + i] = (radii > 0.f) ? 1.f : 0.f;
    outp[3 * HW + 2 * NG + i * 2 + 0] = gx;
    outp[3 * HW + 2 * NG + i * 2 + 1] = gy;

    float* p = params + i * PSTR;
    p[0] = gx;   p[1] = gy;   p[2]  = radii; p[3]  = visible ? opa : 0.f;
    p[4] = conA; p[5] = conB; p[6]  = conC;  p[7]  = visible ? depth : 1e30f;
    p[8] = cr;   p[9] = cg;   p[10] = cb;    p[11] = 0.f;
}

// ---------------------------------------------------------------------------
// Kernel 2: fused cull + local sort + rasterize + combine.
// One block = one 8x8 tile = 512 threads = 8 waves.
//  - stage all 1024 UNSORTED records to LDS
//  - wave-parallel bbox cull (wave w tests gaussians [w*128, w*128+128))
//  - ballot+popcount compaction into survivor list (idx, depth)
//  - rank-sort survivors by (depth, index)  [matches stable argsort]
//  - 8 waves composite 8 contiguous chunks of the sorted list
//  - LDS seg-combine front-to-back + background
// ---------------------------------------------------------------------------
__global__ __launch_bounds__(512) void raster_kernel(
    const float* __restrict__ params, const float* __restrict__ bg,
    float* __restrict__ outp)
{
    __shared__ float4 sp[NG * 3];          // 48 KB: all records (unsorted)
    __shared__ float  sdep[NG];            // 4 KB: survivor depths
    __shared__ int    sidx[NG];            // 4 KB: survivor gaussian idx
    __shared__ int    ssorted[NG];         // 4 KB: depth-ordered survivor idx
    __shared__ float4 segacc[NSEG * 64];   // 8 KB
    __shared__ int    s_cnt;

    const int t = threadIdx.x;
    if (t == 0) s_cnt = 0;
    {
        const float4* src = (const float4*)params;
        for (int k = t; k < NG * 3; k += 512) sp[k] = src[k];
    }
    __syncthreads();

    const int wave = t >> 6;
    const int lane = t & 63;
    const int tileX = blockIdx.x % TILES_X;
    const int tileY = blockIdx.x / TILES_X;
    const float tx0 = (float)(tileX * 8);
    const float ty0 = (float)(tileY * 8);

    // ---- cull + compact: wave w covers gaussians [w*128, (w+1)*128) ----
#pragma unroll
    for (int h = 0; h < 2; ++h) {
        const int gi = wave * 128 + h * 64 + lane;
        float4 g0 = sp[gi * 3];
        bool hit = (g0.w > 0.f) &&
                   (g0.x >= tx0 - g0.z) && (g0.x <= tx0 + 7.f + g0.z) &&
                   (g0.y >= ty0 - g0.z) && (g0.y <= ty0 + 7.f + g0.z);
        unsigned long long mask = __ballot(hit);
        int base = 0;
        if (lane == 0 && mask) base = atomicAdd(&s_cnt, __popcll(mask));
        base = __shfl(base, 0);
        if (hit) {
            int pos = base + __popcll(mask & ((1ULL << lane) - 1ULL));
            sidx[pos] = gi;
            sdep[pos] = sp[gi * 3 + 1].w;   // depth
        }
    }
    __syncthreads();

    const int M = s_cnt;

    // ---- rank-sort survivors by (depth, original index) ----
    for (int s = t; s < M; s += 512) {
        const float ds = sdep[s];
        const int   is = sidx[s];
        int rank = 0;
        for (int j = 0; j < M; ++j) {
            float dj = sdep[j];
            int   ij = sidx[j];
            rank += (dj < ds || (dj == ds && ij < is)) ? 1 : 0;
        }
        ssorted[rank] = is;
    }
    __syncthreads();

    // ---- composite: wave w takes sorted chunk w ----
    const int lx = lane & 7, ly = lane >> 3;
    const int pxi = tileX * 8 + lx;
    const int pyi = tileY * 8 + ly;
    const float px = (float)pxi, py = (float)pyi;

    const int chunk = (M + NSEG - 1) / NSEG;
    const int kbeg = wave * chunk;
    const int kend = min(M, kbeg + chunk);

    float T = 1.f, accR = 0.f, accG = 0.f, accB = 0.f;
    for (int k = kbeg; k < kend; ++k) {
        const int gi = ssorted[k];           // wave-uniform -> broadcast
        float4 g0 = sp[gi * 3 + 0];
        float4 g1 = sp[gi * 3 + 1];
        float4 g2 = sp[gi * 3 + 2];
        float dx = g0.x - px, dy = g0.y - py;
        bool cover = (fabsf(dx) <= g0.z) && (fabsf(dy) <= g0.z);
        float power = -0.5f * (g1.x * dx * dx + g1.z * dy * dy) - g1.y * dx * dy;
        float alpha = fminf(0.99f, g0.w * __expf(fminf(power, 0.f)));
        bool keep = cover && (power <= 0.f) && (alpha >= (1.f / 255.f));
        alpha = keep ? alpha : 0.f;
        float w = alpha * T;
        accR += w * g2.x;
        accG += w * g2.y;
        accB += w * g2.z;
        T *= (1.f - alpha);
    }

    segacc[wave * 64 + lane] = make_float4(accR, accG, accB, T);
    __syncthreads();

    // ---- combine the 8 chunk layers front-to-back ----
    if (t < 64) {
        float Tc = 1.f, r = 0.f, g = 0.f, b = 0.f;
#pragma unroll
        for (int s = 0; s < NSEG; ++s) {
            float4 cc = segacc[s * 64 + t];
            r += Tc * cc.x;
            g += Tc * cc.y;
            b += Tc * cc.z;
            Tc *= cc.w;
        }
        const int pix = pyi * W_IMG + pxi;   // t<64 -> lane==t, same mapping
        outp[pix]          = r + Tc * bg[0];
        outp[HW + pix]     = g + Tc * bg[1];
        outp[2 * HW + pix] = b + Tc * bg[2];
    }
}

// ---------------------------------------------------------------------------
extern "C" void kernel_launch(void* const* d_in, const int* in_sizes, int n_in,
                              void* d_out, int out_size, void* d_ws, size_t ws_size,
                              hipStream_t stream)
{
    const float* means3D   = (const float*)d_in[0];
    const float* scales    = (const float*)d_in[1];
    const float* rotations = (const float*)d_in[2];
    const float* opacities = (const float*)d_in[3];
    const float* shs       = (const float*)d_in[4];
    const float* viewm     = (const float*)d_in[5];
    const float* projm     = (const float*)d_in[6];
    const float* campos    = (const float*)d_in[7];
    const float* bg        = (const float*)d_in[8];

    float* outp   = (float*)d_out;
    float* params = (float*)d_ws;   // NG*PSTR floats (48 KB)

    preprocess_kernel<<<NG / 256, 256, 0, stream>>>(
        means3D, scales, rotations, opacities, shs, viewm, projm, campos,
        params, outp);

    raster_kernel<<<NTILES, 512, 0, stream>>>(params, bg, outp);
}